// Round 8
// baseline (1135.294 us; speedup 1.0000x reference)
//
#include <hip/hip_runtime.h>
#include <math.h>

// PhiDecoderLayer on MI355X. B=2, S=2048, E=2048, MLP=8192, fp32 in/out.
// Round 8: one-phase-lookahead pipeline, race-free slotting.
// The r6/r7 bug: B0(kt+2) was staged in ph1 while ph1/prologue reads of the
// same region were in flight on OTHER waves. Fix: ph1 has no staging; all
// stages target regions whose last reader was lgkm-drained before a barrier
// strictly preceding the stage issue. Same-phase read/write always disjoint.

#define SEQ 2048
#define EMB 2048
#define MLPD 8192

typedef __attribute__((ext_vector_type(8))) short short8;
typedef __attribute__((ext_vector_type(4))) float floatx4;
typedef unsigned short ushort;

__device__ __forceinline__ short f2bf(float f) {
  union { float f; unsigned u; } v; v.f = f;
  unsigned r = v.u + 0x7FFFu + ((v.u >> 16) & 1u);
  return (short)(r >> 16);
}

// async global->LDS, 16B per lane. LDS dest = wave-uniform base + lane*16.
__device__ __forceinline__ void gload16(const ushort* g, ushort* l) {
  __builtin_amdgcn_global_load_lds(
      (__attribute__((address_space(1))) void*)g,
      (__attribute__((address_space(3))) void*)(unsigned)(unsigned long)l,
      16, 0, 0);
}

enum { EPI_QKV = 0, EPI_SCORES = 1, EPI_PV = 2, EPI_RES = 3, EPI_GELU = 4 };

// ============================================================================
// 256x256 tile, BK=64, 8 waves (2Mx4N), per-wave 128x64 output.
// LDS 128 KiB: buf(2) x [A0|A1|B0|B1] half-tiles (128 rows x 64 cols).
// granule-XOR swizzle g ^= (row&7) on stage source and read address.
// Per K-tile kt (buf CB; next tile in NB; stages carry kt+2 data into CB):
//  ph1: rd BH(CB)                      | MFMA AL.BL | lgkm0 bar
//  ph2: rd AH(CB)  stg B0+B1(kt+2)->CB | MFMA AL.BH | lgkm0 vmcnt(4) bar
//  ph3: rd AL(NB)  stg A0(kt+2)->CB    | MFMA AH.BL | lgkm0 bar
//  ph4: rd BL(NB)  stg A1(kt+2)->CB    | MFMA AH.BH | lgkm0 bar
// Liveness: CB.B last read ph1 -> staged ph2 (one barrier after drain).
//           CB.A last read ph2 -> staged ph3/ph4.
// vmcnt(4)@ph2 drains through A1(kt+1) (issued kt-1.ph4, 2-phase lag), so
// ph3/ph4 NB reads are safe after the following barrier.
// ============================================================================
template<int EPI>
__global__ __launch_bounds__(512, 2)
void gemm256(const ushort* __restrict__ A, const ushort* __restrict__ B,
             const float* __restrict__ bias, void* __restrict__ Cp,
             int N, int K, int lda, int ldb, int ldc,
             long sA, long sB, long sC, float scale)
{
  extern __shared__ ushort lds[];   // 65536 ushorts = 128 KiB
  const int t = threadIdx.x;
  const int lane = t & 63, w = t >> 6;
  const int wm = w >> 2, wn = w & 3;
  const long bm = (long)blockIdx.y * 256;
  const long bn = (long)blockIdx.x * 256;
  A += (long)blockIdx.z * sA;
  B += (long)blockIdx.z * sB;

  // staging (write) geometry: pre-swizzled per-lane global source
  const int srow = (w << 3) + (lane >> 3);              // 0..63
  const int gcol = (lane & 7) ^ ((lane >> 3) & 7);      // swizzled granule
  const ushort* Ab = A + (bm + srow) * (long)lda + gcol * 8;
  const ushort* Bb = B + (bn + srow) * (long)ldb + gcol * 8;
  ushort* lw = lds + (w << 9);   // wave slot (1 KiB) within each half-tile

#define STG_A0(LOFF, KK) do { gload16(Ab + (KK), lw + (LOFF)); \
    gload16(Ab + 64L * lda + (KK), lw + (LOFF) + 4096); } while (0)
#define STG_A1(LOFF, KK) do { gload16(Ab + 128L * lda + (KK), lw + (LOFF)); \
    gload16(Ab + 192L * lda + (KK), lw + (LOFF) + 4096); } while (0)
#define STG_B0(LOFF, KK) do { gload16(Bb + (KK), lw + (LOFF)); \
    gload16(Bb + 64L * ldb + (KK), lw + (LOFF) + 4096); } while (0)
#define STG_B1(LOFF, KK) do { gload16(Bb + 128L * ldb + (KK), lw + (LOFF)); \
    gload16(Bb + 192L * ldb + (KK), lw + (LOFF) + 4096); } while (0)

  // read geometry (swizzled ds_read addresses; offsets fold to immediates)
  const int l15 = lane & 15, q = lane >> 4, swz = l15 & 7;
  const int kx0 = (q ^ swz) << 3;
  const int kx1 = ((4 + q) ^ swz) << 3;
  const int arow = (wm << 13) + l15 * 64;
  const int brow = 16384 + ((wn >> 1) << 13) + ((wn & 1) << 12) + l15 * 64;

  floatx4 acc[8][4];
#pragma unroll
  for (int m = 0; m < 8; ++m)
#pragma unroll
    for (int n = 0; n < 4; ++n) acc[m][n] = (floatx4)0.0f;

  // one K-tile of operands, rotated in place (24 b128 = 96 VGPR)
  short8 AL0[4], AL1[4], AH0[4], AH1[4], BL0[2], BL1[2], BH0[2], BH1[2];

#define LDS8(IDX) (*(const short8*)&lds[IDX])
#define RD_AL(CB) do { _Pragma("unroll") for (int mf = 0; mf < 4; ++mf) { \
    AL0[mf] = LDS8((CB) + arow + mf * 1024 + kx0);                        \
    AL1[mf] = LDS8((CB) + arow + mf * 1024 + kx1); } } while (0)
#define RD_AH(CB) do { _Pragma("unroll") for (int mf = 0; mf < 4; ++mf) { \
    AH0[mf] = LDS8((CB) + arow + (4 + mf) * 1024 + kx0);                  \
    AH1[mf] = LDS8((CB) + arow + (4 + mf) * 1024 + kx1); } } while (0)
#define RD_BL(CB) do { _Pragma("unroll") for (int nf = 0; nf < 2; ++nf) { \
    BL0[nf] = LDS8((CB) + brow + nf * 1024 + kx0);                        \
    BL1[nf] = LDS8((CB) + brow + nf * 1024 + kx1); } } while (0)
#define RD_BH(CB) do { _Pragma("unroll") for (int nf = 0; nf < 2; ++nf) { \
    BH0[nf] = LDS8((CB) + brow + (2 + nf) * 1024 + kx0);                  \
    BH1[nf] = LDS8((CB) + brow + (2 + nf) * 1024 + kx1); } } while (0)

#define MMA(MO, NO, X0, X1, Y0, Y1) do {                                  \
    __builtin_amdgcn_s_setprio(1);                                        \
    _Pragma("unroll") for (int mf = 0; mf < 4; ++mf)                      \
      _Pragma("unroll") for (int nf = 0; nf < 2; ++nf) {                  \
        acc[(MO)+mf][(NO)+nf] = __builtin_amdgcn_mfma_f32_16x16x32_bf16(  \
            X0[mf], Y0[nf], acc[(MO)+mf][(NO)+nf], 0, 0, 0);              \
        acc[(MO)+mf][(NO)+nf] = __builtin_amdgcn_mfma_f32_16x16x32_bf16(  \
            X1[mf], Y1[nf], acc[(MO)+mf][(NO)+nf], 0, 0, 0);              \
      }                                                                   \
    __builtin_amdgcn_s_setprio(0);                                        \
  } while (0)

#define BARR() __builtin_amdgcn_s_barrier()
#define LGKM0 asm volatile("s_waitcnt lgkmcnt(0)" ::: "memory")
#define VMC4  asm volatile("s_waitcnt vmcnt(4)" ::: "memory")

#define KTILE(CB, NB, K2) do {                                            \
    /* ph1 */ RD_BH(CB);                                                  \
              MMA(0, 0, AL0, AL1, BL0, BL1); LGKM0; BARR();               \
    /* ph2 */ RD_AH(CB); STG_B0((CB) + 16384, K2); STG_B1((CB) + 24576, K2); \
              MMA(0, 2, AL0, AL1, BH0, BH1); LGKM0; VMC4; BARR();         \
    /* ph3 */ RD_AL(NB); STG_A0((CB) + 0, K2);                            \
              MMA(4, 0, AH0, AH1, BL0, BL1); LGKM0; BARR();               \
    /* ph4 */ RD_BL(NB); STG_A1((CB) + 8192, K2);                         \
              MMA(4, 2, AH0, AH1, BH0, BH1); LGKM0; BARR();               \
  } while (0)

  // ---- prologue: stage tile0 -> buf0, tile1 -> buf1; prime AL,BL(tile0) ----
  STG_B0(16384, 0); STG_B1(24576, 0); STG_A0(0, 0); STG_A1(8192, 0);
  STG_B0(32768 + 16384, 64); STG_B1(32768 + 24576, 64);
  STG_A0(32768 + 0, 64);     STG_A1(32768 + 8192, 64);
  asm volatile("s_waitcnt vmcnt(8)" ::: "memory");   // tile0 complete (own wave)
  BARR();                                            // -> visible to all waves
  RD_AL(0);
  RD_BL(0);
  // prologue reads drain before ph1's MFMA (compiler waits) and are fully
  // lgkm0'd before ph1-end barrier; first stage into buf0's B is at ph2.

  const int NT = K >> 6;  // even for all shapes (16/32/64)
  for (int kt = 0; kt < NT; kt += 2) {
    const int k2 = ((kt + 2 < NT) ? kt + 2 : NT - 1) << 6;  // clamped
    const int k3 = ((kt + 3 < NT) ? kt + 3 : NT - 1) << 6;
    KTILE(0,     32768, k2);
    KTILE(32768, 0,     k3);
  }
  asm volatile("s_waitcnt vmcnt(0)" ::: "memory");   // drain before epilogue
#undef KTILE
#undef MMA
#undef RD_AL
#undef RD_AH
#undef RD_BL
#undef RD_BH
#undef LDS8
#undef STG_A0
#undef STG_A1
#undef STG_B0
#undef STG_B1

  // ---- epilogue: C/D map col=lane&15, row=(lane>>4)*4+i ----
  const int lq = lane >> 4;
#pragma unroll
  for (int mf = 0; mf < 8; ++mf) {
#pragma unroll
    for (int nf = 0; nf < 4; ++nf) {
#pragma unroll
      for (int i = 0; i < 4; ++i) {
        const long r = bm + wm * 128 + mf * 16 + lq * 4 + i;
        const long c = bn + wn * 64 + nf * 16 + l15;
        float val = acc[mf][nf][i];
        if constexpr (EPI == EPI_QKV) {
          val += bias[c];
          ((ushort*)Cp)[r * (long)ldc + c] = (ushort)f2bf(val);
        } else if constexpr (EPI == EPI_SCORES) {  // raw f32 partial
          ((float*)Cp)[(long)blockIdx.z * sC + r * (long)ldc + c] = val * scale;
        } else {  // EPI_GELU exact
          val += bias[c];
          float g = 0.5f * val * (1.0f + erff(val * 0.70710678118f));
          ((ushort*)Cp)[r * (long)ldc + c] = (ushort)f2bf(g);
        }
      }
    }
  }
}

// ============================================================================
// 128x128 m97-structure kernel — kept for scores & PV (512-block grids).
// ============================================================================
template<int EPI>
__global__ __launch_bounds__(256)
void gemm_bt(const ushort* __restrict__ A, const ushort* __restrict__ B,
             const float* __restrict__ bias, const float* __restrict__ res,
             void* __restrict__ Cp, int N, int K,
             int lda, int ldb, int ldc,
             long sA, long sB, long sC, float scale)
{
  __shared__ ushort As[128 * 32];
  __shared__ ushort Bs[128 * 32];

  const int t = threadIdx.x;
  const int lane = t & 63, wid = t >> 6;
  const int wm = wid >> 1, wn = wid & 1;
  const long bm = (long)blockIdx.y * 128;
  const long bn = (long)blockIdx.x * 128;
  A += (long)blockIdx.z * sA;
  B += (long)blockIdx.z * sB;

  const int srow = (wid << 5) + (lane >> 2);
  const int scol = (lane & 3) << 3;
  const ushort* a0 = A + (bm + srow) * (long)lda + scol;
  const ushort* a1 = a0 + 16L * lda;
  const ushort* b0 = B + (bn + srow) * (long)ldb + scol;
  const ushort* b1 = b0 + 16L * ldb;
  ushort* lA0 = As + (wid << 10);
  ushort* lA1 = lA0 + 512;
  ushort* lB0 = Bs + (wid << 10);
  ushort* lB1 = lB0 + 512;

  floatx4 acc[4][4];
#pragma unroll
  for (int m = 0; m < 4; ++m)
#pragma unroll
    for (int n = 0; n < 4; ++n) acc[m][n] = (floatx4)0.0f;

  const int l15 = lane & 15, kq = (lane >> 4) << 3;
  const int abase = ((wm << 6) + l15) * 32 + kq;
  const int bbase = ((wn << 6) + l15) * 32 + kq;

  for (int kb = 0; kb < K; kb += 32) {
    gload16(a0 + kb, lA0);
    gload16(a1 + kb, lA1);
    gload16(b0 + kb, lB0);
    gload16(b1 + kb, lB1);
    __syncthreads();

    short8 a[4], b[4];
#pragma unroll
    for (int m = 0; m < 4; ++m)
      a[m] = *reinterpret_cast<const short8*>(&As[abase + m * (16 * 32)]);
#pragma unroll
    for (int n = 0; n < 4; ++n)
      b[n] = *reinterpret_cast<const short8*>(&Bs[bbase + n * (16 * 32)]);
#pragma unroll
    for (int m = 0; m < 4; ++m)
#pragma unroll
      for (int n = 0; n < 4; ++n)
        acc[m][n] = __builtin_amdgcn_mfma_f32_16x16x32_bf16(a[m], b[n], acc[m][n], 0, 0, 0);
    __syncthreads();
  }

  const int lq = lane >> 4;
#pragma unroll
  for (int m = 0; m < 4; ++m) {
#pragma unroll
    for (int n = 0; n < 4; ++n) {
#pragma unroll
      for (int i = 0; i < 4; ++i) {
        const long r = bm + wm * 64 + m * 16 + lq * 4 + i;
        const long c = bn + wn * 64 + n * 16 + l15;
        float val = acc[m][n][i];
        if constexpr (EPI == EPI_SCORES) {
          ((float*)Cp)[(long)blockIdx.z * sC + r * (long)ldc + c] = val * scale;
        } else if constexpr (EPI == EPI_PV) {
          ((ushort*)Cp)[(long)blockIdx.z * sC + r * (long)ldc + c] = (ushort)f2bf(val);
        }
      }
    }
  }
}

// out = p0 + p1 + bias + res  (f32, 8 elems/thread, N=2048 columns)
__global__ __launch_bounds__(256)
void reduce2(const float* __restrict__ p0, const float* __restrict__ p1,
             const float* __restrict__ bias, const float* __restrict__ res,
             float* __restrict__ out)
{
  const long i = ((long)blockIdx.x * 256 + threadIdx.x) * 8;
  const int c = (int)(i & 2047);
  float4 a0 = *(const float4*)(p0 + i),  a1 = *(const float4*)(p0 + i + 4);
  float4 q0 = *(const float4*)(p1 + i),  q1 = *(const float4*)(p1 + i + 4);
  float4 r0 = *(const float4*)(res + i), r1 = *(const float4*)(res + i + 4);
  float4 b0 = *(const float4*)(bias + c), b1 = *(const float4*)(bias + c + 4);
  float4 o0 = {a0.x + q0.x + r0.x + b0.x, a0.y + q0.y + r0.y + b0.y,
               a0.z + q0.z + r0.z + b0.z, a0.w + q0.w + r0.w + b0.w};
  float4 o1 = {a1.x + q1.x + r1.x + b1.x, a1.y + q1.y + r1.y + b1.y,
               a1.z + q1.z + r1.z + b1.z, a1.w + q1.w + r1.w + b1.w};
  *(float4*)(out + i) = o0;
  *(float4*)(out + i + 4) = o1;
}

__global__ __launch_bounds__(256)
void cvt8(const float* __restrict__ s, ushort* __restrict__ d) {
  const long i = ((long)blockIdx.x * 256 + threadIdx.x) * 8;
  float4 a = *reinterpret_cast<const float4*>(s + i);
  float4 b = *reinterpret_cast<const float4*>(s + i + 4);
  short8 v;
  v[0] = f2bf(a.x); v[1] = f2bf(a.y); v[2] = f2bf(a.z); v[3] = f2bf(a.w);
  v[4] = f2bf(b.x); v[5] = f2bf(b.y); v[6] = f2bf(b.z); v[7] = f2bf(b.w);
  *reinterpret_cast<short8*>(d + i) = v;
}

__global__ __launch_bounds__(256)
void concat3(const float* __restrict__ b0, const float* __restrict__ b1,
             const float* __restrict__ b2, float* __restrict__ dst) {
  const int i = blockIdx.x * 256 + threadIdx.x;
  dst[i] = (i < 2048) ? b0[i] : (i < 4096) ? b1[i - 2048] : b2[i - 4096];
}

__global__ __launch_bounds__(256)
void transpose_v(const ushort* __restrict__ qkv, ushort* __restrict__ vT) {
  __shared__ ushort tile[32][33];
  const int b = blockIdx.z;
  const int s0 = blockIdx.x * 32, e0 = blockIdx.y * 32;
  const int tx = threadIdx.x & 31, ty = threadIdx.x >> 5;
#pragma unroll
  for (int i = 0; i < 4; ++i) {
    const long s = (long)b * SEQ + s0 + ty + i * 8;
    tile[ty + i * 8][tx] = qkv[s * 6144 + 4096 + e0 + tx];
  }
  __syncthreads();
#pragma unroll
  for (int i = 0; i < 4; ++i) {
    const long e = (long)b * SEQ + e0 + ty + i * 8;
    vT[e * SEQ + s0 + tx] = tile[tx][ty + i * 8];
  }
}

__global__ __launch_bounds__(256)
void softmax_rows(const float* __restrict__ S, ushort* __restrict__ P) {
  const long row = blockIdx.x;
  const float* src = S + row * 2048;
  const int t = threadIdx.x, lane = t & 63, wid = t >> 6;
  float4 a = *reinterpret_cast<const float4*>(src + t * 8);
  float4 b = *reinterpret_cast<const float4*>(src + t * 8 + 4);
  float v[8] = {a.x, a.y, a.z, a.w, b.x, b.y, b.z, b.w};
  float m = v[0];
#pragma unroll
  for (int i = 1; i < 8; ++i) m = fmaxf(m, v[i]);
#pragma unroll
  for (int o = 32; o; o >>= 1) m = fmaxf(m, __shfl_xor(m, o));
  __shared__ float rm[4], rs[4];
  if (!lane) rm[wid] = m;
  __syncthreads();
  m = fmaxf(fmaxf(rm[0], rm[1]), fmaxf(rm[2], rm[3]));
  float e[8], s = 0.f;
#pragma unroll
  for (int i = 0; i < 8; ++i) { e[i] = __expf(v[i] - m); s += e[i]; }
#pragma unroll
  for (int o = 32; o; o >>= 1) s += __shfl_xor(s, o);
  if (!lane) rs[wid] = s;
  __syncthreads();
  s = rs[0] + rs[1] + rs[2] + rs[3];
  const float inv = 1.0f / s;
  short8 wv;
#pragma unroll
  for (int i = 0; i < 8; ++i) wv[i] = f2bf(e[i] * inv);
  *reinterpret_cast<short8*>(P + row * 2048 + t * 8) = wv;
}

// layernorm of (p0 + p1 + bias + res), emitting f32 H and bf16 Hb.
__global__ __launch_bounds__(256)
void layernorm_fused(const float* __restrict__ p0, const float* __restrict__ p1,
                     const float* __restrict__ bias, const float* __restrict__ res,
                     const float* __restrict__ g, const float* __restrict__ bb,
                     float* __restrict__ H, ushort* __restrict__ Hb) {
  const long row = blockIdx.x;
  const long base = row * 2048;
  const int t = threadIdx.x, lane = t & 63, wid = t >> 6;
  const long i = base + t * 8;
  const int c0 = t * 8;
  float v[8];
  {
    float4 a0 = *(const float4*)(p0 + i),  a1 = *(const float4*)(p0 + i + 4);
    float4 q0 = *(const float4*)(p1 + i),  q1 = *(const float4*)(p1 + i + 4);
    float4 r0 = *(const float4*)(res + i), r1 = *(const float4*)(res + i + 4);
    float4 b0 = *(const float4*)(bias + c0), b1 = *(const float4*)(bias + c0 + 4);
    v[0] = a0.x + q0.x + r0.x + b0.x; v[1] = a0.y + q0.y + r0.y + b0.y;
    v[2] = a0.z + q0.z + r0.z + b0.z; v[3] = a0.w + q0.w + r0.w + b0.w;
    v[4] = a1.x + q1.x + r1.x + b1.x; v[5] = a1.y + q1.y + r1.y + b1.y;
    v[6] = a1.z + q1.z + r1.z + b1.z; v[7] = a1.w + q1.w + r1.w + b1.w;
  }
  float s = 0.f, ss = 0.f;
#pragma unroll
  for (int i2 = 0; i2 < 8; ++i2) { s += v[i2]; ss += v[i2] * v[i2]; }
#pragma unroll
  for (int o = 32; o; o >>= 1) { s += __shfl_xor(s, o); ss += __shfl_xor(ss, o); }
  __shared__ float r1s[4], r2s[4];
  if (!lane) { r1s[wid] = s; r2s[wid] = ss; }
  __syncthreads();
  s = r1s[0] + r1s[1] + r1s[2] + r1s[3];
  ss = r2s[0] + r2s[1] + r2s[2] + r2s[3];
  const float mu = s * (1.0f / 2048.0f);
  const float var = ss * (1.0f / 2048.0f) - mu * mu;
  const float inv = rsqrtf(var + 1e-5f);
  float o0[8];
  short8 wv;
#pragma unroll
  for (int i2 = 0; i2 < 8; ++i2) {
    const int c = c0 + i2;
    o0[i2] = (v[i2] - mu) * inv * g[c] + bb[c];
    wv[i2] = f2bf(o0[i2]);
  }
  float4 w0 = {o0[0], o0[1], o0[2], o0[3]}, w1 = {o0[4], o0[5], o0[6], o0[7]};
  *reinterpret_cast<float4*>(H + i) = w0;
  *reinterpret_cast<float4*>(H + i + 4) = w1;
  *reinterpret_cast<short8*>(Hb + i) = wv;
}

extern "C" void kernel_launch(void* const* d_in, const int* in_sizes, int n_in,
                              void* d_out, int out_size, void* d_ws, size_t ws_size,
                              hipStream_t stream) {
  const float* x    = (const float*)d_in[0];
  const float* wq   = (const float*)d_in[1];
  const float* bq   = (const float*)d_in[2];
  const float* wk   = (const float*)d_in[3];
  const float* bk   = (const float*)d_in[4];
  const float* wv   = (const float*)d_in[5];
  const float* bv   = (const float*)d_in[6];
  const float* wd   = (const float*)d_in[7];
  const float* bd   = (const float*)d_in[8];
  const float* ln_g = (const float*)d_in[9];
  const float* ln_b = (const float*)d_in[10];
  const float* w1   = (const float*)d_in[11];
  const float* b1   = (const float*)d_in[12];
  const float* w2   = (const float*)d_in[13];
  const float* b2   = (const float*)d_in[14];
  float* out = (float*)d_out;

  (void)hipFuncSetAttribute((const void*)&gemm256<EPI_QKV>,
      hipFuncAttributeMaxDynamicSharedMemorySize, 131072);
  (void)hipFuncSetAttribute((const void*)&gemm256<EPI_GELU>,
      hipFuncAttributeMaxDynamicSharedMemorySize, 131072);
  (void)hipFuncSetAttribute((const void*)&gemm256<EPI_SCORES>,
      hipFuncAttributeMaxDynamicSharedMemorySize, 131072);

  // ---- workspace layout (233 MiB, aliased) ----
  char* p = (char*)d_ws;
  const size_t MB = 1048576;
  ushort* wdb    = (ushort*)(p + 0 * MB);     // 8 MB   [dead after attn-out]
  ushort* w1b    = (ushort*)(p + 8 * MB);     // 32 MB  [dead after mlp1]
  ushort* w2b    = (ushort*)(p + 40 * MB);    // 32 MB  [live till mlp2]
  float*  bqkv   = (float*) (p + 72 * MB);    // 24 KB
  ushort* xb     = (ushort*)(p + 73 * MB);    // 16 MB  -> probs
  ushort* probs  = xb;
  ushort* qkv    = (ushort*)(p + 89 * MB);    // 48 MB  -> partA -> mlpb
  float*  partA  = (float*) (p + 89 * MB);    // 64 MB (z-stride 32 MB)
  ushort* mlpb   = (ushort*)(p + 89 * MB);    // 64 MB
  ushort* vT     = (ushort*)(p + 137 * MB);   // 16 MB  [dead after PV]
  ushort* wqkvb  = (ushort*)(p + 153 * MB);   // 24 MB  [dead after QKV]
  float*  scores = (float*) (p + 153 * MB);   // 32 MB  [dead after softmax]
  ushort* ctx    = (ushort*)(p + 153 * MB);   // 16 MB  [dead after attn-out]
  float*  partM0 = (float*) (p + 0 * MB);     // 32 MB  (wdb/w1b dead by mlp2)
  float*  partM1 = (float*) (p + 153 * MB);   // 32 MB
  float*  h      = (float*) (p + 185 * MB);   // 32 MB  [live till end]
  ushort* hb     = (ushort*)(p + 217 * MB);   // 16 MB  [dead after mlp1]

  const dim3 blk(256), blk512(512);
  const long SQ = (long)SEQ * SEQ;

  // ---- bf16 conversions ----
  cvt8<<<4096, blk, 0, stream>>>(x, xb);
  cvt8<<<2048, blk, 0, stream>>>(wq, wqkvb);
  cvt8<<<2048, blk, 0, stream>>>(wk, wqkvb + 4194304);
  cvt8<<<2048, blk, 0, stream>>>(wv, wqkvb + 8388608);
  cvt8<<<2048, blk, 0, stream>>>(wd, wdb);
  cvt8<<<8192, blk, 0, stream>>>(w1, w1b);
  cvt8<<<8192, blk, 0, stream>>>(w2, w2b);
  concat3<<<24, blk, 0, stream>>>(bq, bk, bv, bqkv);

  // fused QKV: [4096,2048] x [6144,2048]^T -> qkv bf16 [4096][6144]
  gemm256<EPI_QKV><<<dim3(24, 16, 1), blk512, 131072, stream>>>(
      xb, wqkvb, bqkv, qkv, 6144, 2048, 2048, 2048, 6144, 0, 0, 0, 1.f);

  transpose_v<<<dim3(64, 64, 2), blk, 0, stream>>>(qkv, vT);

  // scores = q k^T / sqrt(E), per batch
  gemm_bt<EPI_SCORES><<<dim3(16, 16, 2), blk, 0, stream>>>(
      qkv, qkv + 2048, nullptr, nullptr, scores, 2048, 2048, 6144, 6144, 2048,
      2048L * 6144, 2048L * 6144, SQ, 0.022097086912079608f);

  softmax_rows<<<dim3(4096), blk, 0, stream>>>(scores, probs);

  // ctx = probs @ v
  gemm_bt<EPI_PV><<<dim3(16, 16, 2), blk, 0, stream>>>(
      probs, vT, nullptr, nullptr, ctx, 2048, 2048, 2048, 2048, 2048,
      SQ, SQ, SQ, 1.f);

  // attn-out, split-K=2: partA[z] = ctx[:, z*1024:+1024] @ wd^T-slice
  gemm256<EPI_SCORES><<<dim3(8, 16, 2), blk512, 131072, stream>>>(
      ctx, wdb, nullptr, partA, 2048, 1024, 2048, 2048, 2048,
      1024, 1024, 8388608, 1.f);

  // h = LN(partA0 + partA1 + bd + x); hb = bf16(h)
  layernorm_fused<<<4096, blk, 0, stream>>>(
      partA, partA + 8388608, bd, x, ln_g, ln_b, h, hb);

  // mlpb = gelu(h @ w1^T + b1)
  gemm256<EPI_GELU><<<dim3(32, 16, 1), blk512, 131072, stream>>>(
      hb, w1b, b1, mlpb, 8192, 2048, 2048, 2048, 8192, 0, 0, 0, 1.f);

  // mlp2, split-K=2: partM[z] = mlpb[:, z*4096:+4096] @ w2^T-slice
  gemm256<EPI_SCORES><<<dim3(8, 16, 2), blk512, 131072, stream>>>(
      mlpb, w2b, nullptr, partM0, 2048, 4096, 8192, 8192, 2048,
      4096, 4096, (long)(153 * MB / 4), 1.f);
  // out = partM0 + partM1 + b2 + h
  reduce2<<<4096, blk, 0, stream>>>(partM0, partM1, b2, h, out);
}

// Round 9
// 666.105 us; speedup vs baseline: 1.7044x; 1.7044x over previous
//
#include <hip/hip_runtime.h>
#include <math.h>

// PhiDecoderLayer on MI355X. B=2, S=2048, E=2048, MLP=8192, fp32 in/out.
// Round 9: r4's proven schedule (same barriers, same stage slots, same
// vmcnt(4) ledger) with k-major MFMA clusters: each phase's 16 MFMAs are
// 4m x 4n x 1k (all-independent accs, only 8/8/4/4 ds_reads per phase;
// B k-slices reused from registers across phases). 2x unrolled K-loop for
// static LDS buffer bases. NO register lookahead (r5-r8 lesson: spills).

#define SEQ 2048
#define EMB 2048
#define MLPD 8192

typedef __attribute__((ext_vector_type(8))) short short8;
typedef __attribute__((ext_vector_type(4))) float floatx4;
typedef unsigned short ushort;

__device__ __forceinline__ short f2bf(float f) {
  union { float f; unsigned u; } v; v.f = f;
  unsigned r = v.u + 0x7FFFu + ((v.u >> 16) & 1u);
  return (short)(r >> 16);
}

// async global->LDS, 16B per lane. LDS dest = wave-uniform base + lane*16.
__device__ __forceinline__ void gload16(const ushort* g, ushort* l) {
  __builtin_amdgcn_global_load_lds(
      (__attribute__((address_space(1))) void*)g,
      (__attribute__((address_space(3))) void*)(unsigned)(unsigned long)l,
      16, 0, 0);
}

enum { EPI_QKV = 0, EPI_SCORES = 1, EPI_PV = 2, EPI_RES = 3, EPI_GELU = 4 };

// ============================================================================
// 256x256 tile, BK=64, 8 waves (2Mx4N), per-wave 128x64 output.
// LDS 128 KiB: buf(2) x [A0|A1|B0|B1] half-tiles (128 rows x 64 cols).
// granule-XOR swizzle g ^= (row&7) on stage source and read address.
// Per K-tile kt (cur buf CB, next buf NB; K1 = (kt+1)<<6, K2 = (kt+2)<<6):
//  ph1: rd AL.k0(4)+B.k0(4)  stg A0(kt+1)->NB | bar lgkm0 | 16 MFMA AL0xB0 | bar
//  ph2: rd AL.k1(4)+B.k1(4)  stg A1(kt+1)->NB | bar lgkm0 | 16 MFMA AL1xB1 | bar
//  ph3: rd AH.k0(4)          stg B0(kt+2)->CB | bar lgkm0 | 16 MFMA AH0xB0 | bar
//  ph4: rd AH.k1(4)          stg B1(kt+2)->CB | bar lgkm0 | 16 MFMA AH1xB1
//       | vmcnt(4) bar
// Ledger (= r4's, proven): 12 outstanding at ph4's vmcnt -> drains A(kt+1)
// and the prior tile's B, leaves B(kt+2). Region liveness: CB.B last read
// ph2 (lgkm0-drained before ph2-end bar) -> staged ph3/ph4; CB.A last read
// ph4 -> staged next tile's ph1/ph2 into NB.
// ============================================================================
template<int EPI>
__global__ __launch_bounds__(512, 2)
void gemm256(const ushort* __restrict__ A, const ushort* __restrict__ B,
             const float* __restrict__ bias, void* __restrict__ Cp,
             int N, int K, int lda, int ldb, int ldc,
             long sA, long sB, long sC, float scale)
{
  extern __shared__ ushort lds[];   // 65536 ushorts = 128 KiB
  const int t = threadIdx.x;
  const int lane = t & 63, w = t >> 6;
  const int wm = w >> 2, wn = w & 3;
  const long bm = (long)blockIdx.y * 256;
  const long bn = (long)blockIdx.x * 256;
  A += (long)blockIdx.z * sA;
  B += (long)blockIdx.z * sB;

  // staging (write) geometry: pre-swizzled per-lane global source
  const int srow = (w << 3) + (lane >> 3);              // 0..63
  const int gcol = (lane & 7) ^ ((lane >> 3) & 7);      // swizzled granule
  const ushort* Ab = A + (bm + srow) * (long)lda + gcol * 8;
  const ushort* Bb = B + (bn + srow) * (long)ldb + gcol * 8;
  ushort* lw = lds + (w << 9);   // wave slot (1 KiB) within each half-tile

#define STG_A0(LOFF, KK) do { gload16(Ab + (KK), lw + (LOFF)); \
    gload16(Ab + 64L * lda + (KK), lw + (LOFF) + 4096); } while (0)
#define STG_A1(LOFF, KK) do { gload16(Ab + 128L * lda + (KK), lw + (LOFF)); \
    gload16(Ab + 192L * lda + (KK), lw + (LOFF) + 4096); } while (0)
#define STG_B0(LOFF, KK) do { gload16(Bb + (KK), lw + (LOFF)); \
    gload16(Bb + 64L * ldb + (KK), lw + (LOFF) + 4096); } while (0)
#define STG_B1(LOFF, KK) do { gload16(Bb + 128L * ldb + (KK), lw + (LOFF)); \
    gload16(Bb + 192L * ldb + (KK), lw + (LOFF) + 4096); } while (0)

  // read geometry (swizzled ds_read addresses; offsets fold to immediates)
  const int l15 = lane & 15, q = lane >> 4, swz = l15 & 7;
  const int kx0 = (q ^ swz) << 3;
  const int kx1 = ((4 + q) ^ swz) << 3;
  const int arow = (wm << 13) + l15 * 64;
  const int brow = 16384 + ((wn >> 1) << 13) + ((wn & 1) << 12) + l15 * 64;

  floatx4 acc[8][4];
#pragma unroll
  for (int m = 0; m < 8; ++m)
#pragma unroll
    for (int n = 0; n < 4; ++n) acc[m][n] = (floatx4)0.0f;

  // per-phase operand sets: A transient (4 b128), B k-slices live ph1->ph4
  short8 A0[4], A1[4], B0[4], B1[4];

#define LDS8(IDX) (*(const short8*)&lds[IDX])
#define RD_ALK0(CB) do { _Pragma("unroll") for (int mf = 0; mf < 4; ++mf) \
    A0[mf] = LDS8((CB) + arow + mf * 1024 + kx0); } while (0)
#define RD_ALK1(CB) do { _Pragma("unroll") for (int mf = 0; mf < 4; ++mf) \
    A1[mf] = LDS8((CB) + arow + mf * 1024 + kx1); } while (0)
#define RD_AHK0(CB) do { _Pragma("unroll") for (int mf = 0; mf < 4; ++mf) \
    A0[mf] = LDS8((CB) + arow + (4 + mf) * 1024 + kx0); } while (0)
#define RD_AHK1(CB) do { _Pragma("unroll") for (int mf = 0; mf < 4; ++mf) \
    A1[mf] = LDS8((CB) + arow + (4 + mf) * 1024 + kx1); } while (0)
#define RD_BK0(CB) do { _Pragma("unroll") for (int nf = 0; nf < 4; ++nf) \
    B0[nf] = LDS8((CB) + brow + nf * 1024 + kx0); } while (0)
#define RD_BK1(CB) do { _Pragma("unroll") for (int nf = 0; nf < 4; ++nf) \
    B1[nf] = LDS8((CB) + brow + nf * 1024 + kx1); } while (0)

#define MMA16(MO, AX, BX) do {                                            \
    __builtin_amdgcn_s_setprio(1);                                        \
    _Pragma("unroll") for (int mf = 0; mf < 4; ++mf)                      \
      _Pragma("unroll") for (int nf = 0; nf < 4; ++nf)                    \
        acc[(MO)+mf][nf] = __builtin_amdgcn_mfma_f32_16x16x32_bf16(       \
            AX[mf], BX[nf], acc[(MO)+mf][nf], 0, 0, 0);                   \
    __builtin_amdgcn_s_setprio(0);                                        \
  } while (0)

#define BARR() __builtin_amdgcn_s_barrier()
#define LGKM0 asm volatile("s_waitcnt lgkmcnt(0)" ::: "memory")
#define VMC4  asm volatile("s_waitcnt vmcnt(4)" ::: "memory")

#define KTILE(CB, NB, K1, K2) do {                                        \
    /* ph1 */ RD_ALK0(CB); RD_BK0(CB); STG_A0((NB) + 0, K1);              \
              BARR(); LGKM0; MMA16(0, A0, B0); BARR();                    \
    /* ph2 */ RD_ALK1(CB); RD_BK1(CB); STG_A1((NB) + 8192, K1);           \
              BARR(); LGKM0; MMA16(0, A1, B1); BARR();                    \
    /* ph3 */ RD_AHK0(CB); STG_B0((CB) + 16384, K2);                      \
              BARR(); LGKM0; MMA16(4, A0, B0); BARR();                    \
    /* ph4 */ RD_AHK1(CB); STG_B1((CB) + 24576, K2);                      \
              BARR(); LGKM0; MMA16(4, A1, B1); VMC4; BARR();              \
  } while (0)

  // ---- prologue: tile0 -> buf0 (8 loads), B(tile1) -> buf1 (4 loads) ----
  STG_A0(0, 0);              STG_A1(8192, 0);
  STG_B0(16384, 0);          STG_B1(24576, 0);
  {
    const int k1p = (K > 64) ? 64 : 0;
    STG_B0(32768 + 16384, k1p);
    STG_B1(32768 + 24576, k1p);
  }
  asm volatile("s_waitcnt vmcnt(4)" ::: "memory");   // tile0 complete
  BARR();                                            // visible to all waves

  const int NT = K >> 6;  // even for all shapes (16/32/64)
  for (int kt = 0; kt < NT; kt += 2) {
    const int k1 = ((kt + 1 < NT) ? kt + 1 : NT - 1) << 6;  // clamped
    const int k2 = ((kt + 2 < NT) ? kt + 2 : NT - 1) << 6;
    const int k3 = ((kt + 3 < NT) ? kt + 3 : NT - 1) << 6;
    KTILE(0,     32768, k1, k2);   // tile kt   (cur=buf0)
    KTILE(32768, 0,     k2, k3);   // tile kt+1 (cur=buf1)
  }
  asm volatile("s_waitcnt vmcnt(0)" ::: "memory");   // drain before epilogue
#undef KTILE
#undef MMA16
#undef RD_ALK0
#undef RD_ALK1
#undef RD_AHK0
#undef RD_AHK1
#undef RD_BK0
#undef RD_BK1
#undef LDS8
#undef STG_A0
#undef STG_A1
#undef STG_B0
#undef STG_B1

  // ---- epilogue: C/D map col=lane&15, row=(lane>>4)*4+i ----
  const int lq = lane >> 4;
#pragma unroll
  for (int mf = 0; mf < 8; ++mf) {
#pragma unroll
    for (int nf = 0; nf < 4; ++nf) {
#pragma unroll
      for (int i = 0; i < 4; ++i) {
        const long r = bm + wm * 128 + mf * 16 + lq * 4 + i;
        const long c = bn + wn * 64 + nf * 16 + l15;
        float val = acc[mf][nf][i];
        if constexpr (EPI == EPI_QKV) {
          val += bias[c];
          ((ushort*)Cp)[r * (long)ldc + c] = (ushort)f2bf(val);
        } else if constexpr (EPI == EPI_SCORES) {  // raw f32 partial
          ((float*)Cp)[(long)blockIdx.z * sC + r * (long)ldc + c] = val * scale;
        } else {  // EPI_GELU exact
          val += bias[c];
          float g = 0.5f * val * (1.0f + erff(val * 0.70710678118f));
          ((ushort*)Cp)[r * (long)ldc + c] = (ushort)f2bf(g);
        }
      }
    }
  }
}

// ============================================================================
// 128x128 m97-structure kernel — kept for scores & PV (512-block grids).
// ============================================================================
template<int EPI>
__global__ __launch_bounds__(256)
void gemm_bt(const ushort* __restrict__ A, const ushort* __restrict__ B,
             const float* __restrict__ bias, const float* __restrict__ res,
             void* __restrict__ Cp, int N, int K,
             int lda, int ldb, int ldc,
             long sA, long sB, long sC, float scale)
{
  __shared__ ushort As[128 * 32];
  __shared__ ushort Bs[128 * 32];

  const int t = threadIdx.x;
  const int lane = t & 63, wid = t >> 6;
  const int wm = wid >> 1, wn = wid & 1;
  const long bm = (long)blockIdx.y * 128;
  const long bn = (long)blockIdx.x * 128;
  A += (long)blockIdx.z * sA;
  B += (long)blockIdx.z * sB;

  const int srow = (wid << 5) + (lane >> 2);
  const int scol = (lane & 3) << 3;
  const ushort* a0 = A + (bm + srow) * (long)lda + scol;
  const ushort* a1 = a0 + 16L * lda;
  const ushort* b0 = B + (bn + srow) * (long)ldb + scol;
  const ushort* b1 = b0 + 16L * ldb;
  ushort* lA0 = As + (wid << 10);
  ushort* lA1 = lA0 + 512;
  ushort* lB0 = Bs + (wid << 10);
  ushort* lB1 = lB0 + 512;

  floatx4 acc[4][4];
#pragma unroll
  for (int m = 0; m < 4; ++m)
#pragma unroll
    for (int n = 0; n < 4; ++n) acc[m][n] = (floatx4)0.0f;

  const int l15 = lane & 15, kq = (lane >> 4) << 3;
  const int abase = ((wm << 6) + l15) * 32 + kq;
  const int bbase = ((wn << 6) + l15) * 32 + kq;

  for (int kb = 0; kb < K; kb += 32) {
    gload16(a0 + kb, lA0);
    gload16(a1 + kb, lA1);
    gload16(b0 + kb, lB0);
    gload16(b1 + kb, lB1);
    __syncthreads();

    short8 a[4], b[4];
#pragma unroll
    for (int m = 0; m < 4; ++m)
      a[m] = *reinterpret_cast<const short8*>(&As[abase + m * (16 * 32)]);
#pragma unroll
    for (int n = 0; n < 4; ++n)
      b[n] = *reinterpret_cast<const short8*>(&Bs[bbase + n * (16 * 32)]);
#pragma unroll
    for (int m = 0; m < 4; ++m)
#pragma unroll
      for (int n = 0; n < 4; ++n)
        acc[m][n] = __builtin_amdgcn_mfma_f32_16x16x32_bf16(a[m], b[n], acc[m][n], 0, 0, 0);
    __syncthreads();
  }

  const int lq = lane >> 4;
#pragma unroll
  for (int m = 0; m < 4; ++m) {
#pragma unroll
    for (int n = 0; n < 4; ++n) {
#pragma unroll
      for (int i = 0; i < 4; ++i) {
        const long r = bm + wm * 64 + m * 16 + lq * 4 + i;
        const long c = bn + wn * 64 + n * 16 + l15;
        float val = acc[m][n][i];
        if constexpr (EPI == EPI_SCORES) {
          ((float*)Cp)[(long)blockIdx.z * sC + r * (long)ldc + c] = val * scale;
        } else if constexpr (EPI == EPI_PV) {
          ((ushort*)Cp)[(long)blockIdx.z * sC + r * (long)ldc + c] = (ushort)f2bf(val);
        }
      }
    }
  }
}

// out = p0 + p1 + bias + res  (f32, 8 elems/thread, N=2048 columns)
__global__ __launch_bounds__(256)
void reduce2(const float* __restrict__ p0, const float* __restrict__ p1,
             const float* __restrict__ bias, const float* __restrict__ res,
             float* __restrict__ out)
{
  const long i = ((long)blockIdx.x * 256 + threadIdx.x) * 8;
  const int c = (int)(i & 2047);
  float4 a0 = *(const float4*)(p0 + i),  a1 = *(const float4*)(p0 + i + 4);
  float4 q0 = *(const float4*)(p1 + i),  q1 = *(const float4*)(p1 + i + 4);
  float4 r0 = *(const float4*)(res + i), r1 = *(const float4*)(res + i + 4);
  float4 b0 = *(const float4*)(bias + c), b1 = *(const float4*)(bias + c + 4);
  float4 o0 = {a0.x + q0.x + r0.x + b0.x, a0.y + q0.y + r0.y + b0.y,
               a0.z + q0.z + r0.z + b0.z, a0.w + q0.w + r0.w + b0.w};
  float4 o1 = {a1.x + q1.x + r1.x + b1.x, a1.y + q1.y + r1.y + b1.y,
               a1.z + q1.z + r1.z + b1.z, a1.w + q1.w + r1.w + b1.w};
  *(float4*)(out + i) = o0;
  *(float4*)(out + i + 4) = o1;
}

__global__ __launch_bounds__(256)
void cvt8(const float* __restrict__ s, ushort* __restrict__ d) {
  const long i = ((long)blockIdx.x * 256 + threadIdx.x) * 8;
  float4 a = *reinterpret_cast<const float4*>(s + i);
  float4 b = *reinterpret_cast<const float4*>(s + i + 4);
  short8 v;
  v[0] = f2bf(a.x); v[1] = f2bf(a.y); v[2] = f2bf(a.z); v[3] = f2bf(a.w);
  v[4] = f2bf(b.x); v[5] = f2bf(b.y); v[6] = f2bf(b.z); v[7] = f2bf(b.w);
  *reinterpret_cast<short8*>(d + i) = v;
}

__global__ __launch_bounds__(256)
void concat3(const float* __restrict__ b0, const float* __restrict__ b1,
             const float* __restrict__ b2, float* __restrict__ dst) {
  const int i = blockIdx.x * 256 + threadIdx.x;
  dst[i] = (i < 2048) ? b0[i] : (i < 4096) ? b1[i - 2048] : b2[i - 4096];
}

__global__ __launch_bounds__(256)
void transpose_v(const ushort* __restrict__ qkv, ushort* __restrict__ vT) {
  __shared__ ushort tile[32][33];
  const int b = blockIdx.z;
  const int s0 = blockIdx.x * 32, e0 = blockIdx.y * 32;
  const int tx = threadIdx.x & 31, ty = threadIdx.x >> 5;
#pragma unroll
  for (int i = 0; i < 4; ++i) {
    const long s = (long)b * SEQ + s0 + ty + i * 8;
    tile[ty + i * 8][tx] = qkv[s * 6144 + 4096 + e0 + tx];
  }
  __syncthreads();
#pragma unroll
  for (int i = 0; i < 4; ++i) {
    const long e = (long)b * SEQ + e0 + ty + i * 8;
    vT[e * SEQ + s0 + tx] = tile[tx][ty + i * 8];
  }
}

__global__ __launch_bounds__(256)
void softmax_rows(const float* __restrict__ S, ushort* __restrict__ P) {
  const long row = blockIdx.x;
  const float* src = S + row * 2048;
  const int t = threadIdx.x, lane = t & 63, wid = t >> 6;
  float4 a = *reinterpret_cast<const float4*>(src + t * 8);
  float4 b = *reinterpret_cast<const float4*>(src + t * 8 + 4);
  float v[8] = {a.x, a.y, a.z, a.w, b.x, b.y, b.z, b.w};
  float m = v[0];
#pragma unroll
  for (int i = 1; i < 8; ++i) m = fmaxf(m, v[i]);
#pragma unroll
  for (int o = 32; o; o >>= 1) m = fmaxf(m, __shfl_xor(m, o));
  __shared__ float rm[4], rs[4];
  if (!lane) rm[wid] = m;
  __syncthreads();
  m = fmaxf(fmaxf(rm[0], rm[1]), fmaxf(rm[2], rm[3]));
  float e[8], s = 0.f;
#pragma unroll
  for (int i = 0; i < 8; ++i) { e[i] = __expf(v[i] - m); s += e[i]; }
#pragma unroll
  for (int o = 32; o; o >>= 1) s += __shfl_xor(s, o);
  if (!lane) rs[wid] = s;
  __syncthreads();
  s = rs[0] + rs[1] + rs[2] + rs[3];
  const float inv = 1.0f / s;
  short8 wv;
#pragma unroll
  for (int i = 0; i < 8; ++i) wv[i] = f2bf(e[i] * inv);
  *reinterpret_cast<short8*>(P + row * 2048 + t * 8) = wv;
}

// layernorm of (p0 + p1 + bias + res), emitting f32 H and bf16 Hb.
__global__ __launch_bounds__(256)
void layernorm_fused(const float* __restrict__ p0, const float* __restrict__ p1,
                     const float* __restrict__ bias, const float* __restrict__ res,
                     const float* __restrict__ g, const float* __restrict__ bb,
                     float* __restrict__ H, ushort* __restrict__ Hb) {
  const long row = blockIdx.x;
  const long base = row * 2048;
  const int t = threadIdx.x, lane = t & 63, wid = t >> 6;
  const long i = base + t * 8;
  const int c0 = t * 8;
  float v[8];
  {
    float4 a0 = *(const float4*)(p0 + i),  a1 = *(const float4*)(p0 + i + 4);
    float4 q0 = *(const float4*)(p1 + i),  q1 = *(const float4*)(p1 + i + 4);
    float4 r0 = *(const float4*)(res + i), r1 = *(const float4*)(res + i + 4);
    float4 b0 = *(const float4*)(bias + c0), b1 = *(const float4*)(bias + c0 + 4);
    v[0] = a0.x + q0.x + r0.x + b0.x; v[1] = a0.y + q0.y + r0.y + b0.y;
    v[2] = a0.z + q0.z + r0.z + b0.z; v[3] = a0.w + q0.w + r0.w + b0.w;
    v[4] = a1.x + q1.x + r1.x + b1.x; v[5] = a1.y + q1.y + r1.y + b1.y;
    v[6] = a1.z + q1.z + r1.z + b1.z; v[7] = a1.w + q1.w + r1.w + b1.w;
  }
  float s = 0.f, ss = 0.f;
#pragma unroll
  for (int i2 = 0; i2 < 8; ++i2) { s += v[i2]; ss += v[i2] * v[i2]; }
#pragma unroll
  for (int o = 32; o; o >>= 1) { s += __shfl_xor(s, o); ss += __shfl_xor(ss, o); }
  __shared__ float r1s[4], r2s[4];
  if (!lane) { r1s[wid] = s; r2s[wid] = ss; }
  __syncthreads();
  s = r1s[0] + r1s[1] + r1s[2] + r1s[3];
  ss = r2s[0] + r2s[1] + r2s[2] + r2s[3];
  const float mu = s * (1.0f / 2048.0f);
  const float var = ss * (1.0f / 2048.0f) - mu * mu;
  const float inv = rsqrtf(var + 1e-5f);
  float o0[8];
  short8 wv;
#pragma unroll
  for (int i2 = 0; i2 < 8; ++i2) {
    const int c = c0 + i2;
    o0[i2] = (v[i2] - mu) * inv * g[c] + bb[c];
    wv[i2] = f2bf(o0[i2]);
  }
  float4 w0 = {o0[0], o0[1], o0[2], o0[3]}, w1 = {o0[4], o0[5], o0[6], o0[7]};
  *reinterpret_cast<float4*>(H + i) = w0;
  *reinterpret_cast<float4*>(H + i + 4) = w1;
  *reinterpret_cast<short8*>(Hb + i) = wv;
}

extern "C" void kernel_launch(void* const* d_in, const int* in_sizes, int n_in,
                              void* d_out, int out_size, void* d_ws, size_t ws_size,
                              hipStream_t stream) {
  const float* x    = (const float*)d_in[0];
  const float* wq   = (const float*)d_in[1];
  const float* bq   = (const float*)d_in[2];
  const float* wk   = (const float*)d_in[3];
  const float* bk   = (const float*)d_in[4];
  const float* wv   = (const float*)d_in[5];
  const float* bv   = (const float*)d_in[6];
  const float* wd   = (const float*)d_in[7];
  const float* bd   = (const float*)d_in[8];
  const float* ln_g = (const float*)d_in[9];
  const float* ln_b = (const float*)d_in[10];
  const float* w1   = (const float*)d_in[11];
  const float* b1   = (const float*)d_in[12];
  const float* w2   = (const float*)d_in[13];
  const float* b2   = (const float*)d_in[14];
  float* out = (float*)d_out;

  (void)hipFuncSetAttribute((const void*)&gemm256<EPI_QKV>,
      hipFuncAttributeMaxDynamicSharedMemorySize, 131072);
  (void)hipFuncSetAttribute((const void*)&gemm256<EPI_GELU>,
      hipFuncAttributeMaxDynamicSharedMemorySize, 131072);
  (void)hipFuncSetAttribute((const void*)&gemm256<EPI_SCORES>,
      hipFuncAttributeMaxDynamicSharedMemorySize, 131072);

  // ---- workspace layout (233 MiB, aliased) ----
  char* p = (char*)d_ws;
  const size_t MB = 1048576;
  ushort* wdb    = (ushort*)(p + 0 * MB);     // 8 MB   [dead after attn-out]
  ushort* w1b    = (ushort*)(p + 8 * MB);     // 32 MB  [dead after mlp1]
  ushort* w2b    = (ushort*)(p + 40 * MB);    // 32 MB  [live till mlp2]
  float*  bqkv   = (float*) (p + 72 * MB);    // 24 KB
  ushort* xb     = (ushort*)(p + 73 * MB);    // 16 MB  -> probs
  ushort* probs  = xb;
  ushort* qkv    = (ushort*)(p + 89 * MB);    // 48 MB  -> partA -> mlpb
  float*  partA  = (float*) (p + 89 * MB);    // 64 MB (z-stride 32 MB)
  ushort* mlpb   = (ushort*)(p + 89 * MB);    // 64 MB
  ushort* vT     = (ushort*)(p + 137 * MB);   // 16 MB  [dead after PV]
  ushort* wqkvb  = (ushort*)(p + 153 * MB);   // 24 MB  [dead after QKV]
  float*  scores = (float*) (p + 153 * MB);   // 32 MB  [dead after softmax]
  ushort* ctx    = (ushort*)(p + 153 * MB);   // 16 MB  [dead after attn-out]
  float*  partM0 = (float*) (p + 0 * MB);     // 32 MB  (wdb/w1b dead by mlp2)
  float*  partM1 = (float*) (p + 153 * MB);   // 32 MB
  float*  h      = (float*) (p + 185 * MB);   // 32 MB  [live till end]
  ushort* hb     = (ushort*)(p + 217 * MB);   // 16 MB  [dead after mlp1]

  const dim3 blk(256), blk512(512);
  const long SQ = (long)SEQ * SEQ;

  // ---- bf16 conversions ----
  cvt8<<<4096, blk, 0, stream>>>(x, xb);
  cvt8<<<2048, blk, 0, stream>>>(wq, wqkvb);
  cvt8<<<2048, blk, 0, stream>>>(wk, wqkvb + 4194304);
  cvt8<<<2048, blk, 0, stream>>>(wv, wqkvb + 8388608);
  cvt8<<<2048, blk, 0, stream>>>(wd, wdb);
  cvt8<<<8192, blk, 0, stream>>>(w1, w1b);
  cvt8<<<8192, blk, 0, stream>>>(w2, w2b);
  concat3<<<24, blk, 0, stream>>>(bq, bk, bv, bqkv);

  // fused QKV: [4096,2048] x [6144,2048]^T -> qkv bf16 [4096][6144]
  gemm256<EPI_QKV><<<dim3(24, 16, 1), blk512, 131072, stream>>>(
      xb, wqkvb, bqkv, qkv, 6144, 2048, 2048, 2048, 6144, 0, 0, 0, 1.f);

  transpose_v<<<dim3(64, 64, 2), blk, 0, stream>>>(qkv, vT);

  // scores = q k^T / sqrt(E), per batch
  gemm_bt<EPI_SCORES><<<dim3(16, 16, 2), blk, 0, stream>>>(
      qkv, qkv + 2048, nullptr, nullptr, scores, 2048, 2048, 6144, 6144, 2048,
      2048L * 6144, 2048L * 6144, SQ, 0.022097086912079608f);

  softmax_rows<<<dim3(4096), blk, 0, stream>>>(scores, probs);

  // ctx = probs @ v
  gemm_bt<EPI_PV><<<dim3(16, 16, 2), blk, 0, stream>>>(
      probs, vT, nullptr, nullptr, ctx, 2048, 2048, 2048, 2048, 2048,
      SQ, SQ, SQ, 1.f);

  // attn-out, split-K=2: partA[z] = ctx[:, z*1024:+1024] @ wd^T-slice
  gemm256<EPI_SCORES><<<dim3(8, 16, 2), blk512, 131072, stream>>>(
      ctx, wdb, nullptr, partA, 2048, 1024, 2048, 2048, 2048,
      1024, 1024, 8388608, 1.f);

  // h = LN(partA0 + partA1 + bd + x); hb = bf16(h)
  layernorm_fused<<<4096, blk, 0, stream>>>(
      partA, partA + 8388608, bd, x, ln_g, ln_b, h, hb);

  // mlpb = gelu(h @ w1^T + b1)
  gemm256<EPI_GELU><<<dim3(32, 16, 1), blk512, 131072, stream>>>(
      hb, w1b, b1, mlpb, 8192, 2048, 2048, 2048, 8192, 0, 0, 0, 1.f);

  // mlp2, split-K=2: partM[z] = mlpb[:, z*4096:+4096] @ w2^T-slice
  gemm256<EPI_SCORES><<<dim3(8, 16, 2), blk512, 131072, stream>>>(
      mlpb, w2b, nullptr, partM0, 2048, 4096, 8192, 8192, 2048,
      4096, 4096, (long)(153 * MB / 4), 1.f);
  // out = partM0 + partM1 + b2 + h
  reduce2<<<4096, blk, 0, stream>>>(partM0, partM1, b2, h, out);
}

// Round 10
// 660.891 us; speedup vs baseline: 1.7178x; 1.0079x over previous
//
#include <hip/hip_runtime.h>
#include <math.h>

// PhiDecoderLayer on MI355X. B=2, S=2048, E=2048, MLP=8192, fp32 in/out.
// Round 10: r9's schedule with intra-phase serialization removed: one
// barrier per phase (4/K-tile), no mid-phase barrier, no explicit lgkm0 —
// all ds_reads are consumed by MFMAs in the SAME phase, so compiler-emitted
// counted lgkm waits overlap LDS drain with MFMA issue. Stage slots and the
// vmcnt(4) ledger are unchanged from r9 (proven correct).

#define SEQ 2048
#define EMB 2048
#define MLPD 8192

typedef __attribute__((ext_vector_type(8))) short short8;
typedef __attribute__((ext_vector_type(4))) float floatx4;
typedef unsigned short ushort;

__device__ __forceinline__ short f2bf(float f) {
  union { float f; unsigned u; } v; v.f = f;
  unsigned r = v.u + 0x7FFFu + ((v.u >> 16) & 1u);
  return (short)(r >> 16);
}

// async global->LDS, 16B per lane. LDS dest = wave-uniform base + lane*16.
__device__ __forceinline__ void gload16(const ushort* g, ushort* l) {
  __builtin_amdgcn_global_load_lds(
      (__attribute__((address_space(1))) void*)g,
      (__attribute__((address_space(3))) void*)(unsigned)(unsigned long)l,
      16, 0, 0);
}

enum { EPI_QKV = 0, EPI_SCORES = 1, EPI_PV = 2, EPI_RES = 3, EPI_GELU = 4 };

// ============================================================================
// 256x256 tile, BK=64, 8 waves (2Mx4N), per-wave 128x64 output.
// LDS 128 KiB: buf(2) x [A0|A1|B0|B1] half-tiles (128 rows x 64 cols).
// granule-XOR swizzle g ^= (row&7) on stage source and read address.
// Per K-tile kt (cur CB, next NB; K1=(kt+1)<<6, K2=(kt+2)<<6), ONE barrier
// per phase:
//  ph1: rd AL.k0+B.k0(CB)  stg A0(kt+1)->NB | MMA(0,A0,B0) | bar
//  ph2: rd AL.k1+B.k1(CB)  stg A1(kt+1)->NB | MMA(0,A1,B1) | bar
//  ph3: rd AH.k0(CB)       stg B0(kt+2)->CB | MMA(4,A0,B0) | bar
//  ph4: rd AH.k1(CB)       stg B1(kt+2)->CB | MMA(4,A1,B1) | vmcnt(4) bar
// Safety: every phase's reads are consumed by its own MFMAs (data deps =>
// reads complete before the phase-end barrier); every stage targets a region
// whose last reader finished >=1 barrier earlier; vmcnt(4)+bar at ph4 drains
// A(kt+1)+B(kt+1) before the next tile reads NB (ledger identical to r9).
// ============================================================================
template<int EPI>
__global__ __launch_bounds__(512, 2)
void gemm256(const ushort* __restrict__ A, const ushort* __restrict__ B,
             const float* __restrict__ bias, void* __restrict__ Cp,
             int N, int K, int lda, int ldb, int ldc,
             long sA, long sB, long sC, float scale)
{
  extern __shared__ ushort lds[];   // 65536 ushorts = 128 KiB
  const int t = threadIdx.x;
  const int lane = t & 63, w = t >> 6;
  const int wm = w >> 2, wn = w & 3;
  const long bm = (long)blockIdx.y * 256;
  const long bn = (long)blockIdx.x * 256;
  A += (long)blockIdx.z * sA;
  B += (long)blockIdx.z * sB;

  // staging (write) geometry: pre-swizzled per-lane global source
  const int srow = (w << 3) + (lane >> 3);              // 0..63
  const int gcol = (lane & 7) ^ ((lane >> 3) & 7);      // swizzled granule
  const ushort* Ab = A + (bm + srow) * (long)lda + gcol * 8;
  const ushort* Bb = B + (bn + srow) * (long)ldb + gcol * 8;
  ushort* lw = lds + (w << 9);   // wave slot (1 KiB) within each half-tile

#define STG_A0(LOFF, KK) do { gload16(Ab + (KK), lw + (LOFF)); \
    gload16(Ab + 64L * lda + (KK), lw + (LOFF) + 4096); } while (0)
#define STG_A1(LOFF, KK) do { gload16(Ab + 128L * lda + (KK), lw + (LOFF)); \
    gload16(Ab + 192L * lda + (KK), lw + (LOFF) + 4096); } while (0)
#define STG_B0(LOFF, KK) do { gload16(Bb + (KK), lw + (LOFF)); \
    gload16(Bb + 64L * ldb + (KK), lw + (LOFF) + 4096); } while (0)
#define STG_B1(LOFF, KK) do { gload16(Bb + 128L * ldb + (KK), lw + (LOFF)); \
    gload16(Bb + 192L * ldb + (KK), lw + (LOFF) + 4096); } while (0)

  // read geometry (swizzled ds_read addresses; offsets fold to immediates)
  const int l15 = lane & 15, q = lane >> 4, swz = l15 & 7;
  const int kx0 = (q ^ swz) << 3;
  const int kx1 = ((4 + q) ^ swz) << 3;
  const int arow = (wm << 13) + l15 * 64;
  const int brow = 16384 + ((wn >> 1) << 13) + ((wn & 1) << 12) + l15 * 64;

  floatx4 acc[8][4];
#pragma unroll
  for (int m = 0; m < 8; ++m)
#pragma unroll
    for (int n = 0; n < 4; ++n) acc[m][n] = (floatx4)0.0f;

  // per-phase operand sets: A transient (4 b128), B k-slices live ph1->ph4
  short8 A0[4], A1[4], B0[4], B1[4];

#define LDS8(IDX) (*(const short8*)&lds[IDX])
#define RD_ALK0(CB) do { _Pragma("unroll") for (int mf = 0; mf < 4; ++mf) \
    A0[mf] = LDS8((CB) + arow + mf * 1024 + kx0); } while (0)
#define RD_ALK1(CB) do { _Pragma("unroll") for (int mf = 0; mf < 4; ++mf) \
    A1[mf] = LDS8((CB) + arow + mf * 1024 + kx1); } while (0)
#define RD_AHK0(CB) do { _Pragma("unroll") for (int mf = 0; mf < 4; ++mf) \
    A0[mf] = LDS8((CB) + arow + (4 + mf) * 1024 + kx0); } while (0)
#define RD_AHK1(CB) do { _Pragma("unroll") for (int mf = 0; mf < 4; ++mf) \
    A1[mf] = LDS8((CB) + arow + (4 + mf) * 1024 + kx1); } while (0)
#define RD_BK0(CB) do { _Pragma("unroll") for (int nf = 0; nf < 4; ++nf) \
    B0[nf] = LDS8((CB) + brow + nf * 1024 + kx0); } while (0)
#define RD_BK1(CB) do { _Pragma("unroll") for (int nf = 0; nf < 4; ++nf) \
    B1[nf] = LDS8((CB) + brow + nf * 1024 + kx1); } while (0)

#define MMA16(MO, AX, BX) do {                                            \
    __builtin_amdgcn_s_setprio(1);                                        \
    _Pragma("unroll") for (int mf = 0; mf < 4; ++mf)                      \
      _Pragma("unroll") for (int nf = 0; nf < 4; ++nf)                    \
        acc[(MO)+mf][nf] = __builtin_amdgcn_mfma_f32_16x16x32_bf16(       \
            AX[mf], BX[nf], acc[(MO)+mf][nf], 0, 0, 0);                   \
    __builtin_amdgcn_s_setprio(0);                                        \
  } while (0)

#define BARR() __builtin_amdgcn_s_barrier()
#define VMC4  asm volatile("s_waitcnt vmcnt(4)" ::: "memory")

#define KTILE(CB, NB, K1, K2) do {                                        \
    /* ph1 */ RD_ALK0(CB); RD_BK0(CB); STG_A0((NB) + 0, K1);              \
              MMA16(0, A0, B0); BARR();                                   \
    /* ph2 */ RD_ALK1(CB); RD_BK1(CB); STG_A1((NB) + 8192, K1);           \
              MMA16(0, A1, B1); BARR();                                   \
    /* ph3 */ RD_AHK0(CB); STG_B0((CB) + 16384, K2);                      \
              MMA16(4, A0, B0); BARR();                                   \
    /* ph4 */ RD_AHK1(CB); STG_B1((CB) + 24576, K2);                      \
              MMA16(4, A1, B1); VMC4; BARR();                             \
  } while (0)

  // ---- prologue: tile0 -> buf0 (8 loads), B(tile1) -> buf1 (4 loads) ----
  STG_A0(0, 0);              STG_A1(8192, 0);
  STG_B0(16384, 0);          STG_B1(24576, 0);
  {
    const int k1p = (K > 64) ? 64 : 0;
    STG_B0(32768 + 16384, k1p);
    STG_B1(32768 + 24576, k1p);
  }
  asm volatile("s_waitcnt vmcnt(4)" ::: "memory");   // tile0 complete
  BARR();                                            // visible to all waves

  const int NT = K >> 6;  // even for all shapes (16/32/64)
  for (int kt = 0; kt < NT; kt += 2) {
    const int k1 = ((kt + 1 < NT) ? kt + 1 : NT - 1) << 6;  // clamped
    const int k2 = ((kt + 2 < NT) ? kt + 2 : NT - 1) << 6;
    const int k3 = ((kt + 3 < NT) ? kt + 3 : NT - 1) << 6;
    KTILE(0,     32768, k1, k2);   // tile kt   (cur=buf0)
    KTILE(32768, 0,     k2, k3);   // tile kt+1 (cur=buf1)
  }
  asm volatile("s_waitcnt vmcnt(0)" ::: "memory");   // drain before epilogue
#undef KTILE
#undef MMA16
#undef RD_ALK0
#undef RD_ALK1
#undef RD_AHK0
#undef RD_AHK1
#undef RD_BK0
#undef RD_BK1
#undef LDS8
#undef STG_A0
#undef STG_A1
#undef STG_B0
#undef STG_B1

  // ---- epilogue: C/D map col=lane&15, row=(lane>>4)*4+i ----
  const int lq = lane >> 4;
#pragma unroll
  for (int mf = 0; mf < 8; ++mf) {
#pragma unroll
    for (int nf = 0; nf < 4; ++nf) {
#pragma unroll
      for (int i = 0; i < 4; ++i) {
        const long r = bm + wm * 128 + mf * 16 + lq * 4 + i;
        const long c = bn + wn * 64 + nf * 16 + l15;
        float val = acc[mf][nf][i];
        if constexpr (EPI == EPI_QKV) {
          val += bias[c];
          ((ushort*)Cp)[r * (long)ldc + c] = (ushort)f2bf(val);
        } else if constexpr (EPI == EPI_SCORES) {  // raw f32 partial
          ((float*)Cp)[(long)blockIdx.z * sC + r * (long)ldc + c] = val * scale;
        } else {  // EPI_GELU exact
          val += bias[c];
          float g = 0.5f * val * (1.0f + erff(val * 0.70710678118f));
          ((ushort*)Cp)[r * (long)ldc + c] = (ushort)f2bf(g);
        }
      }
    }
  }
}

// ============================================================================
// 128x128 m97-structure kernel — kept for scores & PV (512-block grids).
// ============================================================================
template<int EPI>
__global__ __launch_bounds__(256)
void gemm_bt(const ushort* __restrict__ A, const ushort* __restrict__ B,
             const float* __restrict__ bias, const float* __restrict__ res,
             void* __restrict__ Cp, int N, int K,
             int lda, int ldb, int ldc,
             long sA, long sB, long sC, float scale)
{
  __shared__ ushort As[128 * 32];
  __shared__ ushort Bs[128 * 32];

  const int t = threadIdx.x;
  const int lane = t & 63, wid = t >> 6;
  const int wm = wid >> 1, wn = wid & 1;
  const long bm = (long)blockIdx.y * 128;
  const long bn = (long)blockIdx.x * 128;
  A += (long)blockIdx.z * sA;
  B += (long)blockIdx.z * sB;

  const int srow = (wid << 5) + (lane >> 2);
  const int scol = (lane & 3) << 3;
  const ushort* a0 = A + (bm + srow) * (long)lda + scol;
  const ushort* a1 = a0 + 16L * lda;
  const ushort* b0 = B + (bn + srow) * (long)ldb + scol;
  const ushort* b1 = b0 + 16L * ldb;
  ushort* lA0 = As + (wid << 10);
  ushort* lA1 = lA0 + 512;
  ushort* lB0 = Bs + (wid << 10);
  ushort* lB1 = lB0 + 512;

  floatx4 acc[4][4];
#pragma unroll
  for (int m = 0; m < 4; ++m)
#pragma unroll
    for (int n = 0; n < 4; ++n) acc[m][n] = (floatx4)0.0f;

  const int l15 = lane & 15, kq = (lane >> 4) << 3;
  const int abase = ((wm << 6) + l15) * 32 + kq;
  const int bbase = ((wn << 6) + l15) * 32 + kq;

  for (int kb = 0; kb < K; kb += 32) {
    gload16(a0 + kb, lA0);
    gload16(a1 + kb, lA1);
    gload16(b0 + kb, lB0);
    gload16(b1 + kb, lB1);
    __syncthreads();

    short8 a[4], b[4];
#pragma unroll
    for (int m = 0; m < 4; ++m)
      a[m] = *reinterpret_cast<const short8*>(&As[abase + m * (16 * 32)]);
#pragma unroll
    for (int n = 0; n < 4; ++n)
      b[n] = *reinterpret_cast<const short8*>(&Bs[bbase + n * (16 * 32)]);
#pragma unroll
    for (int m = 0; m < 4; ++m)
#pragma unroll
      for (int n = 0; n < 4; ++n)
        acc[m][n] = __builtin_amdgcn_mfma_f32_16x16x32_bf16(a[m], b[n], acc[m][n], 0, 0, 0);
    __syncthreads();
  }

  const int lq = lane >> 4;
#pragma unroll
  for (int m = 0; m < 4; ++m) {
#pragma unroll
    for (int n = 0; n < 4; ++n) {
#pragma unroll
      for (int i = 0; i < 4; ++i) {
        const long r = bm + wm * 64 + m * 16 + lq * 4 + i;
        const long c = bn + wn * 64 + n * 16 + l15;
        float val = acc[m][n][i];
        if constexpr (EPI == EPI_SCORES) {
          ((float*)Cp)[(long)blockIdx.z * sC + r * (long)ldc + c] = val * scale;
        } else if constexpr (EPI == EPI_PV) {
          ((ushort*)Cp)[(long)blockIdx.z * sC + r * (long)ldc + c] = (ushort)f2bf(val);
        }
      }
    }
  }
}

// out = p0 + p1 + bias + res  (f32, 8 elems/thread, N=2048 columns)
__global__ __launch_bounds__(256)
void reduce2(const float* __restrict__ p0, const float* __restrict__ p1,
             const float* __restrict__ bias, const float* __restrict__ res,
             float* __restrict__ out)
{
  const long i = ((long)blockIdx.x * 256 + threadIdx.x) * 8;
  const int c = (int)(i & 2047);
  float4 a0 = *(const float4*)(p0 + i),  a1 = *(const float4*)(p0 + i + 4);
  float4 q0 = *(const float4*)(p1 + i),  q1 = *(const float4*)(p1 + i + 4);
  float4 r0 = *(const float4*)(res + i), r1 = *(const float4*)(res + i + 4);
  float4 b0 = *(const float4*)(bias + c), b1 = *(const float4*)(bias + c + 4);
  float4 o0 = {a0.x + q0.x + r0.x + b0.x, a0.y + q0.y + r0.y + b0.y,
               a0.z + q0.z + r0.z + b0.z, a0.w + q0.w + r0.w + b0.w};
  float4 o1 = {a1.x + q1.x + r1.x + b1.x, a1.y + q1.y + r1.y + b1.y,
               a1.z + q1.z + r1.z + b1.z, a1.w + q1.w + r1.w + b1.w};
  *(float4*)(out + i) = o0;
  *(float4*)(out + i + 4) = o1;
}

__global__ __launch_bounds__(256)
void cvt8(const float* __restrict__ s, ushort* __restrict__ d) {
  const long i = ((long)blockIdx.x * 256 + threadIdx.x) * 8;
  float4 a = *reinterpret_cast<const float4*>(s + i);
  float4 b = *reinterpret_cast<const float4*>(s + i + 4);
  short8 v;
  v[0] = f2bf(a.x); v[1] = f2bf(a.y); v[2] = f2bf(a.z); v[3] = f2bf(a.w);
  v[4] = f2bf(b.x); v[5] = f2bf(b.y); v[6] = f2bf(b.z); v[7] = f2bf(b.w);
  *reinterpret_cast<short8*>(d + i) = v;
}

__global__ __launch_bounds__(256)
void concat3(const float* __restrict__ b0, const float* __restrict__ b1,
             const float* __restrict__ b2, float* __restrict__ dst) {
  const int i = blockIdx.x * 256 + threadIdx.x;
  dst[i] = (i < 2048) ? b0[i] : (i < 4096) ? b1[i - 2048] : b2[i - 4096];
}

__global__ __launch_bounds__(256)
void transpose_v(const ushort* __restrict__ qkv, ushort* __restrict__ vT) {
  __shared__ ushort tile[32][33];
  const int b = blockIdx.z;
  const int s0 = blockIdx.x * 32, e0 = blockIdx.y * 32;
  const int tx = threadIdx.x & 31, ty = threadIdx.x >> 5;
#pragma unroll
  for (int i = 0; i < 4; ++i) {
    const long s = (long)b * SEQ + s0 + ty + i * 8;
    tile[ty + i * 8][tx] = qkv[s * 6144 + 4096 + e0 + tx];
  }
  __syncthreads();
#pragma unroll
  for (int i = 0; i < 4; ++i) {
    const long e = (long)b * SEQ + e0 + ty + i * 8;
    vT[e * SEQ + s0 + tx] = tile[tx][ty + i * 8];
  }
}

__global__ __launch_bounds__(256)
void softmax_rows(const float* __restrict__ S, ushort* __restrict__ P) {
  const long row = blockIdx.x;
  const float* src = S + row * 2048;
  const int t = threadIdx.x, lane = t & 63, wid = t >> 6;
  float4 a = *reinterpret_cast<const float4*>(src + t * 8);
  float4 b = *reinterpret_cast<const float4*>(src + t * 8 + 4);
  float v[8] = {a.x, a.y, a.z, a.w, b.x, b.y, b.z, b.w};
  float m = v[0];
#pragma unroll
  for (int i = 1; i < 8; ++i) m = fmaxf(m, v[i]);
#pragma unroll
  for (int o = 32; o; o >>= 1) m = fmaxf(m, __shfl_xor(m, o));
  __shared__ float rm[4], rs[4];
  if (!lane) rm[wid] = m;
  __syncthreads();
  m = fmaxf(fmaxf(rm[0], rm[1]), fmaxf(rm[2], rm[3]));
  float e[8], s = 0.f;
#pragma unroll
  for (int i = 0; i < 8; ++i) { e[i] = __expf(v[i] - m); s += e[i]; }
#pragma unroll
  for (int o = 32; o; o >>= 1) s += __shfl_xor(s, o);
  if (!lane) rs[wid] = s;
  __syncthreads();
  s = rs[0] + rs[1] + rs[2] + rs[3];
  const float inv = 1.0f / s;
  short8 wv;
#pragma unroll
  for (int i = 0; i < 8; ++i) wv[i] = f2bf(e[i] * inv);
  *reinterpret_cast<short8*>(P + row * 2048 + t * 8) = wv;
}

// layernorm of (p0 + p1 + bias + res), emitting f32 H and bf16 Hb.
__global__ __launch_bounds__(256)
void layernorm_fused(const float* __restrict__ p0, const float* __restrict__ p1,
                     const float* __restrict__ bias, const float* __restrict__ res,
                     const float* __restrict__ g, const float* __restrict__ bb,
                     float* __restrict__ H, ushort* __restrict__ Hb) {
  const long row = blockIdx.x;
  const long base = row * 2048;
  const int t = threadIdx.x, lane = t & 63, wid = t >> 6;
  const long i = base + t * 8;
  const int c0 = t * 8;
  float v[8];
  {
    float4 a0 = *(const float4*)(p0 + i),  a1 = *(const float4*)(p0 + i + 4);
    float4 q0 = *(const float4*)(p1 + i),  q1 = *(const float4*)(p1 + i + 4);
    float4 r0 = *(const float4*)(res + i), r1 = *(const float4*)(res + i + 4);
    float4 b0 = *(const float4*)(bias + c0), b1 = *(const float4*)(bias + c0 + 4);
    v[0] = a0.x + q0.x + r0.x + b0.x; v[1] = a0.y + q0.y + r0.y + b0.y;
    v[2] = a0.z + q0.z + r0.z + b0.z; v[3] = a0.w + q0.w + r0.w + b0.w;
    v[4] = a1.x + q1.x + r1.x + b1.x; v[5] = a1.y + q1.y + r1.y + b1.y;
    v[6] = a1.z + q1.z + r1.z + b1.z; v[7] = a1.w + q1.w + r1.w + b1.w;
  }
  float s = 0.f, ss = 0.f;
#pragma unroll
  for (int i2 = 0; i2 < 8; ++i2) { s += v[i2]; ss += v[i2] * v[i2]; }
#pragma unroll
  for (int o = 32; o; o >>= 1) { s += __shfl_xor(s, o); ss += __shfl_xor(ss, o); }
  __shared__ float r1s[4], r2s[4];
  if (!lane) { r1s[wid] = s; r2s[wid] = ss; }
  __syncthreads();
  s = r1s[0] + r1s[1] + r1s[2] + r1s[3];
  ss = r2s[0] + r2s[1] + r2s[2] + r2s[3];
  const float mu = s * (1.0f / 2048.0f);
  const float var = ss * (1.0f / 2048.0f) - mu * mu;
  const float inv = rsqrtf(var + 1e-5f);
  float o0[8];
  short8 wv;
#pragma unroll
  for (int i2 = 0; i2 < 8; ++i2) {
    const int c = c0 + i2;
    o0[i2] = (v[i2] - mu) * inv * g[c] + bb[c];
    wv[i2] = f2bf(o0[i2]);
  }
  float4 w0 = {o0[0], o0[1], o0[2], o0[3]}, w1 = {o0[4], o0[5], o0[6], o0[7]};
  *reinterpret_cast<float4*>(H + i) = w0;
  *reinterpret_cast<float4*>(H + i + 4) = w1;
  *reinterpret_cast<short8*>(Hb + i) = wv;
}

extern "C" void kernel_launch(void* const* d_in, const int* in_sizes, int n_in,
                              void* d_out, int out_size, void* d_ws, size_t ws_size,
                              hipStream_t stream) {
  const float* x    = (const float*)d_in[0];
  const float* wq   = (const float*)d_in[1];
  const float* bq   = (const float*)d_in[2];
  const float* wk   = (const float*)d_in[3];
  const float* bk   = (const float*)d_in[4];
  const float* wv   = (const float*)d_in[5];
  const float* bv   = (const float*)d_in[6];
  const float* wd   = (const float*)d_in[7];
  const float* bd   = (const float*)d_in[8];
  const float* ln_g = (const float*)d_in[9];
  const float* ln_b = (const float*)d_in[10];
  const float* w1   = (const float*)d_in[11];
  const float* b1   = (const float*)d_in[12];
  const float* w2   = (const float*)d_in[13];
  const float* b2   = (const float*)d_in[14];
  float* out = (float*)d_out;

  (void)hipFuncSetAttribute((const void*)&gemm256<EPI_QKV>,
      hipFuncAttributeMaxDynamicSharedMemorySize, 131072);
  (void)hipFuncSetAttribute((const void*)&gemm256<EPI_GELU>,
      hipFuncAttributeMaxDynamicSharedMemorySize, 131072);
  (void)hipFuncSetAttribute((const void*)&gemm256<EPI_SCORES>,
      hipFuncAttributeMaxDynamicSharedMemorySize, 131072);

  // ---- workspace layout (233 MiB, aliased) ----
  char* p = (char*)d_ws;
  const size_t MB = 1048576;
  ushort* wdb    = (ushort*)(p + 0 * MB);     // 8 MB   [dead after attn-out]
  ushort* w1b    = (ushort*)(p + 8 * MB);     // 32 MB  [dead after mlp1]
  ushort* w2b    = (ushort*)(p + 40 * MB);    // 32 MB  [live till mlp2]
  float*  bqkv   = (float*) (p + 72 * MB);    // 24 KB
  ushort* xb     = (ushort*)(p + 73 * MB);    // 16 MB  -> probs
  ushort* probs  = xb;
  ushort* qkv    = (ushort*)(p + 89 * MB);    // 48 MB  -> partA -> mlpb
  float*  partA  = (float*) (p + 89 * MB);    // 64 MB (z-stride 32 MB)
  ushort* mlpb   = (ushort*)(p + 89 * MB);    // 64 MB
  ushort* vT     = (ushort*)(p + 137 * MB);   // 16 MB  [dead after PV]
  ushort* wqkvb  = (ushort*)(p + 153 * MB);   // 24 MB  [dead after QKV]
  float*  scores = (float*) (p + 153 * MB);   // 32 MB  [dead after softmax]
  ushort* ctx    = (ushort*)(p + 153 * MB);   // 16 MB  [dead after attn-out]
  float*  partM0 = (float*) (p + 0 * MB);     // 32 MB  (wdb/w1b dead by mlp2)
  float*  partM1 = (float*) (p + 153 * MB);   // 32 MB
  float*  h      = (float*) (p + 185 * MB);   // 32 MB  [live till end]
  ushort* hb     = (ushort*)(p + 217 * MB);   // 16 MB  [dead after mlp1]

  const dim3 blk(256), blk512(512);
  const long SQ = (long)SEQ * SEQ;

  // ---- bf16 conversions ----
  cvt8<<<4096, blk, 0, stream>>>(x, xb);
  cvt8<<<2048, blk, 0, stream>>>(wq, wqkvb);
  cvt8<<<2048, blk, 0, stream>>>(wk, wqkvb + 4194304);
  cvt8<<<2048, blk, 0, stream>>>(wv, wqkvb + 8388608);
  cvt8<<<2048, blk, 0, stream>>>(wd, wdb);
  cvt8<<<8192, blk, 0, stream>>>(w1, w1b);
  cvt8<<<8192, blk, 0, stream>>>(w2, w2b);
  concat3<<<24, blk, 0, stream>>>(bq, bk, bv, bqkv);

  // fused QKV: [4096,2048] x [6144,2048]^T -> qkv bf16 [4096][6144]
  gemm256<EPI_QKV><<<dim3(24, 16, 1), blk512, 131072, stream>>>(
      xb, wqkvb, bqkv, qkv, 6144, 2048, 2048, 2048, 6144, 0, 0, 0, 1.f);

  transpose_v<<<dim3(64, 64, 2), blk, 0, stream>>>(qkv, vT);

  // scores = q k^T / sqrt(E), per batch
  gemm_bt<EPI_SCORES><<<dim3(16, 16, 2), blk, 0, stream>>>(
      qkv, qkv + 2048, nullptr, nullptr, scores, 2048, 2048, 6144, 6144, 2048,
      2048L * 6144, 2048L * 6144, SQ, 0.022097086912079608f);

  softmax_rows<<<dim3(4096), blk, 0, stream>>>(scores, probs);

  // ctx = probs @ v
  gemm_bt<EPI_PV><<<dim3(16, 16, 2), blk, 0, stream>>>(
      probs, vT, nullptr, nullptr, ctx, 2048, 2048, 2048, 2048, 2048,
      SQ, SQ, SQ, 1.f);

  // attn-out, split-K=2: partA[z] = ctx[:, z*1024:+1024] @ wd^T-slice
  gemm256<EPI_SCORES><<<dim3(8, 16, 2), blk512, 131072, stream>>>(
      ctx, wdb, nullptr, partA, 2048, 1024, 2048, 2048, 2048,
      1024, 1024, 8388608, 1.f);

  // h = LN(partA0 + partA1 + bd + x); hb = bf16(h)
  layernorm_fused<<<4096, blk, 0, stream>>>(
      partA, partA + 8388608, bd, x, ln_g, ln_b, h, hb);

  // mlpb = gelu(h @ w1^T + b1)
  gemm256<EPI_GELU><<<dim3(32, 16, 1), blk512, 131072, stream>>>(
      hb, w1b, b1, mlpb, 8192, 2048, 2048, 2048, 8192, 0, 0, 0, 1.f);

  // mlp2, split-K=2: partM[z] = mlpb[:, z*4096:+4096] @ w2^T-slice
  gemm256<EPI_SCORES><<<dim3(8, 16, 2), blk512, 131072, stream>>>(
      mlpb, w2b, nullptr, partM0, 2048, 4096, 8192, 8192, 2048,
      4096, 4096, (long)(153 * MB / 4), 1.f);
  // out = partM0 + partM1 + b2 + h
  reduce2<<<4096, blk, 0, stream>>>(partM0, partM1, b2, h, out);
}